// Round 1
// baseline (665.372 us; speedup 1.0000x reference)
//
#include <hip/hip_runtime.h>
#include <math.h>

#define BATCH 8192
#define DIM 4096

// ---------------------------------------------------------------------------
// ws float layout (495 floats):
//   l=1: base   0: P0(9), A1(9), B1(9)                          -> 27
//   l=2: base  27: P0(25), A1,B1,A2,B2 (25 each)                -> 125
//   l=3: base 152: P0(49), A1,B1,A2,B2,A3,B3 (49 each)          -> 343
// X(beta) = P0 + sum_mu cos(mu*beta)*A_mu + sin(mu*beta)*B_mu
// ---------------------------------------------------------------------------

__device__ void mm_n(int n, const double* A, const double* B, double* C) {
  for (int i = 0; i < n; ++i)
    for (int j = 0; j < n; ++j) {
      double s = 0.0;
      for (int k = 0; k < n; ++k) s += A[i * n + k] * B[k * n + j];
      C[i * n + j] = s;
    }
}

__global__ void init_consts(float* __restrict__ wsF) {
  __shared__ double w[3][12][49];
  int t = threadIdx.x;
  if (t >= 3) return;
  const int l = t + 1, n = 2 * l + 1, nn = n * n;

  // --- build Jx (real symmetric) and U (complex: UR + i*UI) ---
  double* JX = w[t][0];
  double* UR = w[t][1];
  double* UI = w[t][2];
  for (int i = 0; i < nn; ++i) { JX[i] = 0.0; UR[i] = 0.0; UI[i] = 0.0; }
  for (int a = 0; a < n - 1; ++a) {
    double m = (double)(a - l);
    double v = 0.5 * sqrt((double)(l * (l + 1)) - m * (m + 1.0));
    JX[(a + 1) * n + a] = v;
    JX[a * n + (a + 1)] = v;
  }
  UR[l * n + l] = 1.0;
  const double s = 0.70710678118654752440;  // 1/sqrt(2)
  for (int mu = 1; mu <= l; ++mu) {
    double sg = (mu & 1) ? -1.0 : 1.0;
    UR[(l + mu) * n + (l - mu)] = s;
    UR[(l + mu) * n + (l + mu)] = s * sg;
    UI[(l - mu) * n + (l - mu)] = s;
    UI[(l - mu) * n + (l + mu)] = -s * sg;
  }

  // --- K = Im(U Jx U^H)  (real antisymmetric generator; X(b)=exp(bK)) ---
  double* MR = w[t][3];
  double* MI = w[t][4];
  mm_n(n, UR, JX, MR);
  mm_n(n, UI, JX, MI);
  double* K = w[t][5];
  for (int a = 0; a < n; ++a)
    for (int b = 0; b < n; ++b) {
      double acc = 0.0;
      for (int c = 0; c < n; ++c)
        acc += MI[a * n + c] * UR[b * n + c] - MR[a * n + c] * UI[b * n + c];
      K[a * n + b] = acc;
    }

  // --- E1 = exp((pi/4) K) via scaling(1/16) + Taylor(12) + 4 squarings ---
  const double TH = 0.78539816339744830962;  // pi/4
  double* S = w[t][0];  // JX dead
  for (int i = 0; i < nn; ++i) S[i] = K[i] * (TH / 16.0);
  double* P = w[t][1];  // UR dead (K already computed)
  double* T = w[t][2];  // UI dead
  for (int i = 0; i < n; ++i)
    for (int j = 0; j < n; ++j) P[i * n + j] = (i == j) ? 1.0 : 0.0;
  for (int tt = 12; tt >= 1; --tt) {
    mm_n(n, S, P, T);
    double inv = 1.0 / (double)tt;
    for (int i = 0; i < n; ++i)
      for (int j = 0; j < n; ++j)
        P[i * n + j] = ((i == j) ? 1.0 : 0.0) + T[i * n + j] * inv;
  }
  for (int q = 0; q < 4; ++q) {
    mm_n(n, P, P, T);
    double* tmp = P; P = T; T = tmp;
  }  // 4 swaps -> P back at w[t][1]
  double* E1 = P;

  // --- DFT over 8 samples E_k = E1^k to extract P0, A_mu, B_mu ---
  double* Ek = w[t][3];
  double* Et = w[t][4];
  for (int i = 0; i < n; ++i)
    for (int j = 0; j < n; ++j) Ek[i * n + j] = (i == j) ? 1.0 : 0.0;
  for (int tt = 0; tt <= 2 * l; ++tt) {
    double* A = w[t][5 + tt];
    for (int i = 0; i < nn; ++i) A[i] = 0.0;
  }
  for (int k = 0; k < 8; ++k) {
    double* A0 = w[t][5];
    for (int i = 0; i < nn; ++i) A0[i] += 0.125 * Ek[i];
    for (int mu = 1; mu <= l; ++mu) {
      double ang = TH * (double)(mu * k);
      double cc = 0.25 * cos(ang), ss = 0.25 * sin(ang);
      double* Am = w[t][5 + 2 * mu - 1];
      double* Bm = w[t][5 + 2 * mu];
      for (int i = 0; i < nn; ++i) {
        Am[i] += cc * Ek[i];
        Bm[i] += ss * Ek[i];
      }
    }
    mm_n(n, Ek, E1, Et);
    double* tmp = Ek; Ek = Et; Et = tmp;
  }

  int base = (l == 1) ? 0 : ((l == 2) ? 27 : 152);
  for (int tt = 0; tt <= 2 * l; ++tt) {
    double* A = w[t][5 + tt];
    for (int i = 0; i < nn; ++i) wsF[base + tt * nn + i] = (float)A[i];
  }
}

// ---------------------------------------------------------------------------
// Main kernel: 1 block = 4 batch rows, 256 threads (64 lanes/row, float4/lane)
// ---------------------------------------------------------------------------

__device__ __forceinline__ float4 f4fma(float a, float4 v, float4 acc) {
  return make_float4(fmaf(a, v.x, acc.x), fmaf(a, v.y, acc.y),
                     fmaf(a, v.z, acc.z), fmaf(a, v.w, acc.w));
}

__global__ __launch_bounds__(256) void rot_apply(
    const float* __restrict__ gamma, const float* __restrict__ beta,
    const float* __restrict__ alpha, const float* __restrict__ x,
    const float* __restrict__ wsF, float* __restrict__ out) {
  __shared__ float Dl[4][83];  // per row: l1 at 0..8, l2 at 9..33, l3 at 34..82
  const int tid = threadIdx.x;
  const int b0 = blockIdx.x * 4;

  // ---- phase 1: build D entries (332 = 4 rows x 83 entries) ----
  for (int e = tid; e < 332; e += 256) {
    int row = e / 83;
    int idx = e - row * 83;
    int l, n, basec, r;
    if (idx < 9)       { l = 1; n = 3; basec = 0;   r = idx; }
    else if (idx < 34) { l = 2; n = 5; basec = 27;  r = idx - 9; }
    else               { l = 3; n = 7; basec = 152; r = idx - 34; }
    int i = r / n, j = r - i * n;
    int b = b0 + row;
    float al = alpha[b], be = beta[b], ga = gamma[b];

    float cb1, sb1;
    sincosf(be, &sb1, &cb1);
    float cb2 = cb1 * cb1 - sb1 * sb1, sb2 = 2.f * sb1 * cb1;
    float cb3 = cb2 * cb1 - sb2 * sb1, sb3 = sb2 * cb1 + cb2 * sb1;
    float cb[4] = {1.f, cb1, cb2, cb3};
    float sb[4] = {0.f, sb1, sb2, sb3};

    const float* C = wsF + basec;
    int ip = n - 1 - i, jp = n - 1 - j;
    float xij = 0.f, xijp = 0.f, xipj = 0.f, xipjp = 0.f;
    for (int tt = 0; tt <= 2 * l; ++tt) {
      float coef = (tt == 0) ? 1.f : ((tt & 1) ? cb[(tt + 1) >> 1] : sb[tt >> 1]);
      const float* M = C + tt * n * n;
      xij   = fmaf(coef, M[i * n + j],   xij);
      xijp  = fmaf(coef, M[i * n + jp],  xijp);
      xipj  = fmaf(coef, M[ip * n + j],  xipj);
      xipjp = fmaf(coef, M[ip * n + jp], xipjp);
    }
    // D = Y(alpha) X Y(gamma); Y diag[k]=cos((k-l)t), anti[k]=sin((k-l)t)
    float sa, ca, sg, cg;
    sincosf((float)(i - l) * al, &sa, &ca);
    sincosf((float)(j - l) * ga, &sg, &cg);
    Dl[row][idx] = (ca * xij + sa * xipj) * cg - (ca * xijp + sa * xipjp) * sg;
  }
  __syncthreads();

  // ---- phase 2: streaming apply, float4 per lane ----
  const int lane = tid & 63;
  const int row = tid >> 6;
  const size_t b = (size_t)(b0 + row);
  const float4* __restrict__ xin = (const float4*)x + b * 1024;
  float4* __restrict__ xo = (float4*)out + b * 1024;
  const float* D = Dl[row];

  // l=0: identity copy (float4 idx 0..63)
  xo[lane] = xin[lane];

  // l=1: float4 base 64, 3 rows
  {
    float4 v0 = xin[64 + lane], v1 = xin[128 + lane], v2 = xin[192 + lane];
    #pragma unroll
    for (int i = 0; i < 3; ++i) {
      float4 o = make_float4(0.f, 0.f, 0.f, 0.f);
      o = f4fma(D[i * 3 + 0], v0, o);
      o = f4fma(D[i * 3 + 1], v1, o);
      o = f4fma(D[i * 3 + 2], v2, o);
      xo[64 + i * 64 + lane] = o;
    }
  }

  // l=2: float4 base 256, 5 rows
  {
    float4 v[5];
    #pragma unroll
    for (int j = 0; j < 5; ++j) v[j] = xin[256 + j * 64 + lane];
    #pragma unroll
    for (int i = 0; i < 5; ++i) {
      float4 o = make_float4(0.f, 0.f, 0.f, 0.f);
      #pragma unroll
      for (int j = 0; j < 5; ++j) o = f4fma(D[9 + i * 5 + j], v[j], o);
      xo[256 + i * 64 + lane] = o;
    }
  }

  // l=3: float4 base 576, 7 rows
  {
    float4 v[7];
    #pragma unroll
    for (int j = 0; j < 7; ++j) v[j] = xin[576 + j * 64 + lane];
    #pragma unroll
    for (int i = 0; i < 7; ++i) {
      float4 o = make_float4(0.f, 0.f, 0.f, 0.f);
      #pragma unroll
      for (int j = 0; j < 7; ++j) o = f4fma(D[34 + i * 7 + j], v[j], o);
      xo[576 + i * 64 + lane] = o;
    }
  }
}

extern "C" void kernel_launch(void* const* d_in, const int* in_sizes, int n_in,
                              void* d_out, int out_size, void* d_ws, size_t ws_size,
                              hipStream_t stream) {
  const float* gamma = (const float*)d_in[0];
  const float* beta  = (const float*)d_in[1];
  const float* alpha = (const float*)d_in[2];
  const float* x     = (const float*)d_in[3];
  float* out = (float*)d_out;
  float* wsF = (float*)d_ws;

  init_consts<<<1, 64, 0, stream>>>(wsF);
  rot_apply<<<BATCH / 4, 256, 0, stream>>>(gamma, beta, alpha, x, wsF, out);
}

// Round 2
// 52.225 us; speedup vs baseline: 12.7405x; 12.7405x over previous
//
#include <hip/hip_runtime.h>
#include <math.h>

#define BATCH 8192
#define DIM 4096

// ---------------------------------------------------------------------------
// Compile-time computation of the x-rotation constant tables.
//   X_l(beta) = P0 + sum_mu cos(mu*beta)*A_mu + sin(mu*beta)*B_mu
// Layout (495 floats):
//   l=1: base   0: P0(9),  A1,B1 (9 each)                    -> 27
//   l=2: base  27: P0(25), A1,B1,A2,B2 (25 each)             -> 125
//   l=3: base 152: P0(49), A1,B1,A2,B2,A3,B3 (49 each)       -> 343
// Derivation: K = Im(U Jx U^H) (real antisymmetric), E1 = exp(pi/4 K) via
// scaling+Taylor+squaring, then DFT over E1^k, k=0..7. All in constexpr fp64.
// ---------------------------------------------------------------------------

struct FT { float v[495]; };

constexpr double csqrt(double x) {
  double g = x > 1.0 ? x : 1.0;
  for (int i = 0; i < 50; ++i) g = 0.5 * (g + x / g);
  return g;
}

constexpr void mmc(int n, const double* A, const double* B, double* C) {
  for (int i = 0; i < n; ++i)
    for (int j = 0; j < n; ++j) {
      double s = 0.0;
      for (int k = 0; k < n; ++k) s += A[i * n + k] * B[k * n + j];
      C[i * n + j] = s;
    }
}

constexpr FT compute_ft() {
  FT o{};
  for (int l = 1; l <= 3; ++l) {
    const int n = 2 * l + 1, nn = n * n;
    double JX[49] = {}, UR[49] = {}, UI[49] = {};
    for (int a = 0; a < n - 1; ++a) {
      double m = (double)(a - l);
      double v = 0.5 * csqrt((double)(l * (l + 1)) - m * (m + 1.0));
      JX[(a + 1) * n + a] = v;
      JX[a * n + (a + 1)] = v;
    }
    UR[l * n + l] = 1.0;
    const double s = csqrt(0.5);
    for (int mu = 1; mu <= l; ++mu) {
      double sg = (mu & 1) ? -1.0 : 1.0;
      UR[(l + mu) * n + (l - mu)] = s;
      UR[(l + mu) * n + (l + mu)] = s * sg;
      UI[(l - mu) * n + (l - mu)] = s;
      UI[(l - mu) * n + (l + mu)] = -s * sg;
    }
    // K = Im(U Jx U^H)
    double MR[49] = {}, MI[49] = {};
    mmc(n, UR, JX, MR);
    mmc(n, UI, JX, MI);
    double K[49] = {};
    for (int a = 0; a < n; ++a)
      for (int b = 0; b < n; ++b) {
        double acc = 0.0;
        for (int c = 0; c < n; ++c)
          acc += MI[a * n + c] * UR[b * n + c] - MR[a * n + c] * UI[b * n + c];
        K[a * n + b] = acc;
      }
    // E1 = exp((pi/4) K): scale 1/16, Taylor order 12 (Horner), 4 squarings
    const double TH = 0.78539816339744830962;
    double S[49] = {}, P[49] = {}, T[49] = {};
    for (int i = 0; i < nn; ++i) S[i] = K[i] * (TH / 16.0);
    for (int i = 0; i < n; ++i) P[i * n + i] = 1.0;
    for (int t = 12; t >= 1; --t) {
      mmc(n, S, P, T);
      double inv = 1.0 / (double)t;
      for (int i = 0; i < nn; ++i) P[i] = T[i] * inv;
      for (int i = 0; i < n; ++i) P[i * n + i] += 1.0;
    }
    for (int q = 0; q < 4; ++q) {
      mmc(n, P, P, T);
      for (int i = 0; i < nn; ++i) P[i] = T[i];
    }
    // DFT over E1^k, k=0..7; cos/sin(k*pi/4) are exact table values
    double acc[7][49] = {};
    double Ek[49] = {}, Et[49] = {};
    for (int i = 0; i < n; ++i) Ek[i * n + i] = 1.0;
    const double r2 = csqrt(0.5);
    const double c8[8] = {1.0, r2, 0.0, -r2, -1.0, -r2, 0.0, r2};
    const double s8[8] = {0.0, r2, 1.0, r2, 0.0, -r2, -1.0, -r2};
    for (int k = 0; k < 8; ++k) {
      for (int i = 0; i < nn; ++i) acc[0][i] += 0.125 * Ek[i];
      for (int mu = 1; mu <= l; ++mu) {
        int a8 = (mu * k) & 7;
        double cc = 0.25 * c8[a8], ss = 0.25 * s8[a8];
        for (int i = 0; i < nn; ++i) {
          acc[2 * mu - 1][i] += cc * Ek[i];
          acc[2 * mu][i] += ss * Ek[i];
        }
      }
      mmc(n, Ek, P, Et);
      for (int i = 0; i < nn; ++i) Ek[i] = Et[i];
    }
    int base = (l == 1) ? 0 : ((l == 2) ? 27 : 152);
    for (int t = 0; t <= 2 * l; ++t)
      for (int i = 0; i < nn; ++i) o.v[base + t * nn + i] = (float)acc[t][i];
  }
  return o;
}

__device__ __constant__ FT c_tb = compute_ft();

// ---------------------------------------------------------------------------
// Main kernel: 1 block = 4 batch rows, 256 threads (64 lanes/row, float4/lane)
// ---------------------------------------------------------------------------

__device__ __forceinline__ float4 f4fma(float a, float4 v, float4 acc) {
  return make_float4(fmaf(a, v.x, acc.x), fmaf(a, v.y, acc.y),
                     fmaf(a, v.z, acc.z), fmaf(a, v.w, acc.w));
}

__global__ __launch_bounds__(256) void rot_apply(
    const float* __restrict__ gamma, const float* __restrict__ beta,
    const float* __restrict__ alpha, const float* __restrict__ x,
    float* __restrict__ out) {
  __shared__ float Dl[4][83];  // per row: l1 at 0..8, l2 at 9..33, l3 at 34..82
  const int tid = threadIdx.x;
  const int b0 = blockIdx.x * 4;

  // ---- phase 1: build D entries (332 = 4 rows x 83 entries) ----
  for (int e = tid; e < 332; e += 256) {
    int row = e / 83;
    int idx = e - row * 83;
    int l, n, basec, r;
    if (idx < 9)       { l = 1; n = 3; basec = 0;   r = idx; }
    else if (idx < 34) { l = 2; n = 5; basec = 27;  r = idx - 9; }
    else               { l = 3; n = 7; basec = 152; r = idx - 34; }
    int i = r / n, j = r - i * n;
    int b = b0 + row;
    float al = alpha[b], be = beta[b], ga = gamma[b];

    float cb1, sb1;
    sincosf(be, &sb1, &cb1);
    float cb2 = cb1 * cb1 - sb1 * sb1, sb2 = 2.f * sb1 * cb1;
    float cb3 = cb2 * cb1 - sb2 * sb1, sb3 = sb2 * cb1 + cb2 * sb1;
    float cb[4] = {1.f, cb1, cb2, cb3};
    float sb[4] = {0.f, sb1, sb2, sb3};

    const float* C = c_tb.v + basec;
    int ip = n - 1 - i, jp = n - 1 - j;
    float xij = 0.f, xijp = 0.f, xipj = 0.f, xipjp = 0.f;
    for (int tt = 0; tt <= 2 * l; ++tt) {
      float coef = (tt == 0) ? 1.f : ((tt & 1) ? cb[(tt + 1) >> 1] : sb[tt >> 1]);
      const float* M = C + tt * n * n;
      xij   = fmaf(coef, M[i * n + j],   xij);
      xijp  = fmaf(coef, M[i * n + jp],  xijp);
      xipj  = fmaf(coef, M[ip * n + j],  xipj);
      xipjp = fmaf(coef, M[ip * n + jp], xipjp);
    }
    // D = Y(alpha) X Y(gamma); Y diag[k]=cos((k-l)t), anti[k]=sin((k-l)t)
    float sa, ca, sg, cg;
    sincosf((float)(i - l) * al, &sa, &ca);
    sincosf((float)(j - l) * ga, &sg, &cg);
    Dl[row][idx] = (ca * xij + sa * xipj) * cg - (ca * xijp + sa * xipjp) * sg;
  }
  __syncthreads();

  // ---- phase 2: streaming apply, float4 per lane ----
  const int lane = tid & 63;
  const int row = tid >> 6;
  const size_t b = (size_t)(b0 + row);
  const float4* __restrict__ xin = (const float4*)x + b * 1024;
  float4* __restrict__ xo = (float4*)out + b * 1024;
  const float* D = Dl[row];

  // l=0: identity copy (float4 idx 0..63)
  xo[lane] = xin[lane];

  // l=1: float4 base 64, 3 rows
  {
    float4 v0 = xin[64 + lane], v1 = xin[128 + lane], v2 = xin[192 + lane];
    #pragma unroll
    for (int i = 0; i < 3; ++i) {
      float4 o = make_float4(0.f, 0.f, 0.f, 0.f);
      o = f4fma(D[i * 3 + 0], v0, o);
      o = f4fma(D[i * 3 + 1], v1, o);
      o = f4fma(D[i * 3 + 2], v2, o);
      xo[64 + i * 64 + lane] = o;
    }
  }

  // l=2: float4 base 256, 5 rows
  {
    float4 v[5];
    #pragma unroll
    for (int j = 0; j < 5; ++j) v[j] = xin[256 + j * 64 + lane];
    #pragma unroll
    for (int i = 0; i < 5; ++i) {
      float4 o = make_float4(0.f, 0.f, 0.f, 0.f);
      #pragma unroll
      for (int j = 0; j < 5; ++j) o = f4fma(D[9 + i * 5 + j], v[j], o);
      xo[256 + i * 64 + lane] = o;
    }
  }

  // l=3: float4 base 576, 7 rows
  {
    float4 v[7];
    #pragma unroll
    for (int j = 0; j < 7; ++j) v[j] = xin[576 + j * 64 + lane];
    #pragma unroll
    for (int i = 0; i < 7; ++i) {
      float4 o = make_float4(0.f, 0.f, 0.f, 0.f);
      #pragma unroll
      for (int j = 0; j < 7; ++j) o = f4fma(D[34 + i * 7 + j], v[j], o);
      xo[576 + i * 64 + lane] = o;
    }
  }
}

extern "C" void kernel_launch(void* const* d_in, const int* in_sizes, int n_in,
                              void* d_out, int out_size, void* d_ws, size_t ws_size,
                              hipStream_t stream) {
  const float* gamma = (const float*)d_in[0];
  const float* beta  = (const float*)d_in[1];
  const float* alpha = (const float*)d_in[2];
  const float* x     = (const float*)d_in[3];
  float* out = (float*)d_out;

  rot_apply<<<BATCH / 4, 256, 0, stream>>>(gamma, beta, alpha, x, out);
}

// Round 4
// 49.105 us; speedup vs baseline: 13.5500x; 1.0635x over previous
//
#include <hip/hip_runtime.h>
#include <math.h>

#define BATCH 8192
#define DIM 4096

// ---------------------------------------------------------------------------
// Compile-time computation of the x-rotation constant tables.
//   X_l(beta) = P0 + sum_mu cos(mu*beta)*A_mu + sin(mu*beta)*B_mu
// Layout (495 floats):
//   l=1: base   0: P0(9),  A1,B1 (9 each)                    -> 27
//   l=2: base  27: P0(25), A1,B1,A2,B2 (25 each)             -> 125
//   l=3: base 152: P0(49), A1,B1,A2,B2,A3,B3 (49 each)       -> 343
// ---------------------------------------------------------------------------

struct FT { float v[495]; };

constexpr double csqrt(double x) {
  double g = x > 1.0 ? x : 1.0;
  for (int i = 0; i < 50; ++i) g = 0.5 * (g + x / g);
  return g;
}

constexpr void mmc(int n, const double* A, const double* B, double* C) {
  for (int i = 0; i < n; ++i)
    for (int j = 0; j < n; ++j) {
      double s = 0.0;
      for (int k = 0; k < n; ++k) s += A[i * n + k] * B[k * n + j];
      C[i * n + j] = s;
    }
}

constexpr FT compute_ft() {
  FT o{};
  for (int l = 1; l <= 3; ++l) {
    const int n = 2 * l + 1, nn = n * n;
    double JX[49] = {}, UR[49] = {}, UI[49] = {};
    for (int a = 0; a < n - 1; ++a) {
      double m = (double)(a - l);
      double v = 0.5 * csqrt((double)(l * (l + 1)) - m * (m + 1.0));
      JX[(a + 1) * n + a] = v;
      JX[a * n + (a + 1)] = v;
    }
    UR[l * n + l] = 1.0;
    const double s = csqrt(0.5);
    for (int mu = 1; mu <= l; ++mu) {
      double sg = (mu & 1) ? -1.0 : 1.0;
      UR[(l + mu) * n + (l - mu)] = s;
      UR[(l + mu) * n + (l + mu)] = s * sg;
      UI[(l - mu) * n + (l - mu)] = s;
      UI[(l - mu) * n + (l + mu)] = -s * sg;
    }
    double MR[49] = {}, MI[49] = {};
    mmc(n, UR, JX, MR);
    mmc(n, UI, JX, MI);
    double K[49] = {};
    for (int a = 0; a < n; ++a)
      for (int b = 0; b < n; ++b) {
        double acc = 0.0;
        for (int c = 0; c < n; ++c)
          acc += MI[a * n + c] * UR[b * n + c] - MR[a * n + c] * UI[b * n + c];
        K[a * n + b] = acc;
      }
    const double TH = 0.78539816339744830962;
    double S[49] = {}, P[49] = {}, T[49] = {};
    for (int i = 0; i < nn; ++i) S[i] = K[i] * (TH / 16.0);
    for (int i = 0; i < n; ++i) P[i * n + i] = 1.0;
    for (int t = 12; t >= 1; --t) {
      mmc(n, S, P, T);
      double inv = 1.0 / (double)t;
      for (int i = 0; i < nn; ++i) P[i] = T[i] * inv;
      for (int i = 0; i < n; ++i) P[i * n + i] += 1.0;
    }
    for (int q = 0; q < 4; ++q) {
      mmc(n, P, P, T);
      for (int i = 0; i < nn; ++i) P[i] = T[i];
    }
    double acc[7][49] = {};
    double Ek[49] = {}, Et[49] = {};
    for (int i = 0; i < n; ++i) Ek[i * n + i] = 1.0;
    const double r2 = csqrt(0.5);
    const double c8[8] = {1.0, r2, 0.0, -r2, -1.0, -r2, 0.0, r2};
    const double s8[8] = {0.0, r2, 1.0, r2, 0.0, -r2, -1.0, -r2};
    for (int k = 0; k < 8; ++k) {
      for (int i = 0; i < nn; ++i) acc[0][i] += 0.125 * Ek[i];
      for (int mu = 1; mu <= l; ++mu) {
        int a8 = (mu * k) & 7;
        double cc = 0.25 * c8[a8], ss = 0.25 * s8[a8];
        for (int i = 0; i < nn; ++i) {
          acc[2 * mu - 1][i] += cc * Ek[i];
          acc[2 * mu][i] += ss * Ek[i];
        }
      }
      mmc(n, Ek, P, Et);
      for (int i = 0; i < nn; ++i) Ek[i] = Et[i];
    }
    int base = (l == 1) ? 0 : ((l == 2) ? 27 : 152);
    for (int t = 0; t <= 2 * l; ++t)
      for (int i = 0; i < nn; ++i) o.v[base + t * nn + i] = (float)acc[t][i];
  }
  return o;
}

__device__ __constant__ FT c_tb = compute_ft();

// native clang vector type — accepted by __builtin_nontemporal_store
typedef float vf4 __attribute__((ext_vector_type(4)));

// ---------------------------------------------------------------------------
// Main kernel: 1 block = 4 batch rows, 256 threads (64 lanes/row, vf4/lane)
// All 16 float4 loads issued up front; non-temporal stores keep the output
// out of the Infinity Cache so the input stays L3-resident across replays.
// ---------------------------------------------------------------------------

__device__ __forceinline__ vf4 vfma4(float a, vf4 v, vf4 acc) {
  return acc + a * v;  // clang vector ops lower to v_fma_f32 x4 under -O3 fast fma
}

__global__ __launch_bounds__(256) void rot_apply(
    const float* __restrict__ gamma, const float* __restrict__ beta,
    const float* __restrict__ alpha, const float* __restrict__ x,
    float* __restrict__ out) {
  __shared__ float Dl[4][83];  // per row: l1 at 0..8, l2 at 9..33, l3 at 34..82
  const int tid = threadIdx.x;
  const int b0 = blockIdx.x * 4;

  // ---- phase 1: build D entries (332 = 4 rows x 83 entries) ----
  for (int e = tid; e < 332; e += 256) {
    int row = e / 83;
    int idx = e - row * 83;
    int l, n, basec, r;
    if (idx < 9)       { l = 1; n = 3; basec = 0;   r = idx; }
    else if (idx < 34) { l = 2; n = 5; basec = 27;  r = idx - 9; }
    else               { l = 3; n = 7; basec = 152; r = idx - 34; }
    int i = r / n, j = r - i * n;
    int b = b0 + row;
    float al = alpha[b], be = beta[b], ga = gamma[b];

    float cb1, sb1;
    sincosf(be, &sb1, &cb1);
    float cb2 = cb1 * cb1 - sb1 * sb1, sb2 = 2.f * sb1 * cb1;
    float cb3 = cb2 * cb1 - sb2 * sb1, sb3 = sb2 * cb1 + cb2 * sb1;
    float cb[4] = {1.f, cb1, cb2, cb3};
    float sb[4] = {0.f, sb1, sb2, sb3};

    const float* C = c_tb.v + basec;
    int ip = n - 1 - i, jp = n - 1 - j;
    float xij = 0.f, xijp = 0.f, xipj = 0.f, xipjp = 0.f;
    for (int tt = 0; tt <= 2 * l; ++tt) {
      float coef = (tt == 0) ? 1.f : ((tt & 1) ? cb[(tt + 1) >> 1] : sb[tt >> 1]);
      const float* M = C + tt * n * n;
      xij   = fmaf(coef, M[i * n + j],   xij);
      xijp  = fmaf(coef, M[i * n + jp],  xijp);
      xipj  = fmaf(coef, M[ip * n + j],  xipj);
      xipjp = fmaf(coef, M[ip * n + jp], xipjp);
    }
    float sa, ca, sg, cg;
    sincosf((float)(i - l) * al, &sa, &ca);
    sincosf((float)(j - l) * ga, &sg, &cg);
    Dl[row][idx] = (ca * xij + sa * xipj) * cg - (ca * xijp + sa * xipjp) * sg;
  }
  __syncthreads();

  // ---- phase 2: streaming apply ----
  const int lane = tid & 63;
  const int row = tid >> 6;
  const size_t b = (size_t)(b0 + row);
  const vf4* __restrict__ xin = (const vf4*)x + b * 1024;
  vf4* __restrict__ xo = (vf4*)out + b * 1024;
  const float* D = Dl[row];

  // issue ALL loads first: 1 + 3 + 5 + 7 = 16 vf4 in flight
  vf4 v0 = xin[lane];
  vf4 v1[3], v2[5], v3[7];
  #pragma unroll
  for (int j = 0; j < 3; ++j) v1[j] = xin[64 + j * 64 + lane];
  #pragma unroll
  for (int j = 0; j < 5; ++j) v2[j] = xin[256 + j * 64 + lane];
  #pragma unroll
  for (int j = 0; j < 7; ++j) v3[j] = xin[576 + j * 64 + lane];

  // l=0: identity copy
  __builtin_nontemporal_store(v0, &xo[lane]);

  // l=1
  #pragma unroll
  for (int i = 0; i < 3; ++i) {
    vf4 o = (vf4)(0.f);
    #pragma unroll
    for (int j = 0; j < 3; ++j) o = vfma4(D[i * 3 + j], v1[j], o);
    __builtin_nontemporal_store(o, &xo[64 + i * 64 + lane]);
  }

  // l=2
  #pragma unroll
  for (int i = 0; i < 5; ++i) {
    vf4 o = (vf4)(0.f);
    #pragma unroll
    for (int j = 0; j < 5; ++j) o = vfma4(D[9 + i * 5 + j], v2[j], o);
    __builtin_nontemporal_store(o, &xo[256 + i * 64 + lane]);
  }

  // l=3
  #pragma unroll
  for (int i = 0; i < 7; ++i) {
    vf4 o = (vf4)(0.f);
    #pragma unroll
    for (int j = 0; j < 7; ++j) o = vfma4(D[34 + i * 7 + j], v3[j], o);
    __builtin_nontemporal_store(o, &xo[576 + i * 64 + lane]);
  }
}

extern "C" void kernel_launch(void* const* d_in, const int* in_sizes, int n_in,
                              void* d_out, int out_size, void* d_ws, size_t ws_size,
                              hipStream_t stream) {
  const float* gamma = (const float*)d_in[0];
  const float* beta  = (const float*)d_in[1];
  const float* alpha = (const float*)d_in[2];
  const float* x     = (const float*)d_in[3];
  float* out = (float*)d_out;

  rot_apply<<<BATCH / 4, 256, 0, stream>>>(gamma, beta, alpha, x, out);
}